// Round 8
// baseline (514.793 us; speedup 1.0000x reference)
//
#include <hip/hip_runtime.h>
#include <hip/hip_fp16.h>

#define NN 50000
#define NE 200000
#define IND 512
#define HIDD 2000
#define LATD 128

#define M_PAD 50176    // 392*128 = 784*64
#define N1_PAD 2048    // HIDD padded (pad cols forced to exact 0)
#define NBLK 196       // ceil(NN/256)

typedef _Float16 f16x8 __attribute__((ext_vector_type(8)));
typedef _Float16 f16x2 __attribute__((ext_vector_type(2)));
typedef float f32x4 __attribute__((ext_vector_type(4)));

__device__ __forceinline__ void gload_lds16(const _Float16* g, _Float16* l) {
    __builtin_amdgcn_global_load_lds(
        (const __attribute__((address_space(1))) unsigned int*)g,
        (__attribute__((address_space(3))) unsigned int*)l,
        16, 0, 0);
}

// ---- in-degree (int): deg[col[e]] += 1 ----
__global__ void k_degree(const int* __restrict__ col, int* __restrict__ deg) {
    int e = blockIdx.x * 256 + threadIdx.x;
    if (e < NE) atomicAdd(&deg[col[e]], 1);
}

// ---- hierarchical exclusive scan: (1) per-block sums ----
__global__ void k_bsum(const int* __restrict__ deg, int* __restrict__ bsum) {
    __shared__ int sm[4];
    int i = blockIdx.x * 256 + threadIdx.x;
    int v = (i < NN) ? deg[i] : 0;
    #pragma unroll
    for (int off = 32; off; off >>= 1) v += __shfl_down(v, off, 64);
    if ((threadIdx.x & 63) == 0) sm[threadIdx.x >> 6] = v;
    __syncthreads();
    if (threadIdx.x == 0) bsum[blockIdx.x] = sm[0] + sm[1] + sm[2] + sm[3];
}

// ---- (2) exclusive scan of the 196 block sums (one block) ----
__global__ void k_bscan(int* __restrict__ bsum) {
    __shared__ int sm[256];
    int tid = threadIdx.x;
    int v = (tid < NBLK) ? bsum[tid] : 0;
    sm[tid] = v;
    __syncthreads();
    #pragma unroll
    for (int off = 1; off < 256; off <<= 1) {
        int t = (tid >= off) ? sm[tid - off] : 0;
        __syncthreads();
        sm[tid] += t;
        __syncthreads();
    }
    if (tid < NBLK) bsum[tid] = sm[tid] - v;   // exclusive
}

// ---- (3) per-block exclusive scan + offset -> row_ptr; also dis = rsqrt(deg+1) ----
__global__ void k_scan_final(const int* __restrict__ deg, const int* __restrict__ bsum,
                             int* __restrict__ row_ptr, float* __restrict__ dis) {
    __shared__ int sm[256];
    int b = blockIdx.x, tid = threadIdx.x;
    int i = b * 256 + tid;
    int v = (i < NN) ? deg[i] : 0;
    if (i < NN) dis[i] = rsqrtf((float)v + 1.0f);
    sm[tid] = v;
    __syncthreads();
    #pragma unroll
    for (int off = 1; off < 256; off <<= 1) {
        int t = (tid >= off) ? sm[tid - off] : 0;
        __syncthreads();
        sm[tid] += t;
        __syncthreads();
    }
    if (i < NN) row_ptr[i] = bsum[b] + sm[tid] - v;
    if (i == NN - 1) row_ptr[NN] = bsum[b] + sm[tid];
}

// ---- fill CSR: csr_src[row_ptr[c] + cursor[c]++] = r ----
__global__ void k_fill(const int* __restrict__ ei, const int* __restrict__ row_ptr,
                       int* __restrict__ cursor, int* __restrict__ csr_src) {
    int e = blockIdx.x * 256 + threadIdx.x;
    if (e < NE) {
        int r = ei[e], c = ei[NE + e];
        int pos = atomicAdd(&cursor[c], 1);
        csr_src[row_ptr[c] + pos] = r;
    }
}

// ---- LDS-tiled transpose+convert: in f32 [R][C] -> out fp16, out[c*ldo + r].
//      Writes the FULL padded range, zero-filling pads (no separate memset). ----
__global__ void k_transpose_tiled(const float* __restrict__ in,
                                  _Float16* __restrict__ out, int R, int C, int ldo,
                                  int Rpad, int Cpad) {
    __shared__ float sm[32][33];
    int c0 = blockIdx.x * 32, r0 = blockIdx.y * 32;
    int tx = threadIdx.x & 31, ty = threadIdx.x >> 5;   // 32 x 8
    #pragma unroll
    for (int i = 0; i < 4; ++i) {
        int r = r0 + ty + i * 8, c = c0 + tx;
        sm[ty + i * 8][tx] = (r < R && c < C) ? in[(size_t)r * C + c] : 0.f;
    }
    __syncthreads();
    #pragma unroll
    for (int i = 0; i < 4; ++i) {
        int c = c0 + ty + i * 8, r = r0 + tx;
        if (c < Cpad && r < Rpad) out[(size_t)c * ldo + r] = (_Float16)sm[tx][ty + i * 8];
    }
}

// ---- x f32 -> xh fp16 (8 elems/thread) ----
__global__ void k_xcvt(const float* __restrict__ in, _Float16* __restrict__ out, int n8) {
    int i = blockIdx.x * 256 + threadIdx.x;
    if (i < n8) {
        float4 a = ((const float4*)in)[i * 2];
        float4 b = ((const float4*)in)[i * 2 + 1];
        f16x8 o;
        o[0] = (_Float16)a.x; o[1] = (_Float16)a.y; o[2] = (_Float16)a.z; o[3] = (_Float16)a.w;
        o[4] = (_Float16)b.x; o[5] = (_Float16)b.y; o[6] = (_Float16)b.z; o[7] = (_Float16)b.w;
        ((f16x8*)out)[i] = o;
    }
}

// ---- gather-aggregate x (fp16 src), 4-wide independent load slots.
//      dst range [dst0, dst0+ndst) for split-dispatch profiling. ----
__global__ void k_gather_x(const _Float16* __restrict__ xh, const int* __restrict__ row_ptr,
                           const int* __restrict__ csr_src, const float* __restrict__ dis,
                           _Float16* __restrict__ Ah, int dst0, int ndst) {
    int dst = dst0 + blockIdx.x * 4 + (threadIdx.x >> 6);
    if (dst >= dst0 + ndst || dst >= NN) return;
    int lane = threadIdx.x & 63;
    float dd = dis[dst];
    const f16x8* vb = (const f16x8*)xh;                 // node stride 64 (512 halves / 8)
    f16x8 sv = vb[(size_t)dst * 64 + lane];
    float acc[8];
    #pragma unroll
    for (int q = 0; q < 8; ++q) acc[q] = dd * (float)sv[q];
    int beg = row_ptr[dst], end = row_ptr[dst + 1];
    for (int c = beg; c < end; c += 64) {
        int n = end - c; if (n > 64) n = 64;
        int li = (lane < n) ? csr_src[c + lane] : 0;    // lane-parallel idx load
        float lns = (lane < n) ? dis[li] : 0.f;         // lane-parallel dis gather
        for (int j = 0; j < n; j += 4) {
            int j1 = j + 1 < n ? j + 1 : n - 1;
            int j2 = j + 2 < n ? j + 2 : n - 1;
            int j3 = j + 3 < n ? j + 3 : n - 1;
            int s0 = __shfl(li, j),  s1 = __shfl(li, j1);
            int s2 = __shfl(li, j2), s3 = __shfl(li, j3);
            float w0 = __shfl(lns, j);
            float w1 = (j + 1 < n) ? __shfl(lns, j1) : 0.f;
            float w2 = (j + 2 < n) ? __shfl(lns, j2) : 0.f;
            float w3 = (j + 3 < n) ? __shfl(lns, j3) : 0.f;
            f16x8 v0 = vb[(size_t)s0 * 64 + lane];
            f16x8 v1 = vb[(size_t)s1 * 64 + lane];
            f16x8 v2 = vb[(size_t)s2 * 64 + lane];
            f16x8 v3 = vb[(size_t)s3 * 64 + lane];
            #pragma unroll
            for (int q = 0; q < 8; ++q)
                acc[q] += w0 * (float)v0[q] + w1 * (float)v1[q]
                        + w2 * (float)v2[q] + w3 * (float)v3[q];
        }
    }
    f16x8 o;
    #pragma unroll
    for (int q = 0; q < 8; ++q) o[q] = (_Float16)(dd * acc[q]);
    *(f16x8*)(Ah + (size_t)dst * IND + lane * 8) = o;
}

// ---- gather-aggregate t (fp16) + bias + sigmoid -> out (f32), 4-wide slots ----
__global__ void k_gather_t(const _Float16* __restrict__ t, const int* __restrict__ row_ptr,
                           const int* __restrict__ csr_src, const float* __restrict__ dis,
                           const float* __restrict__ b2, float* __restrict__ out,
                           int dst0, int ndst) {
    int dst = dst0 + blockIdx.x * 4 + (threadIdx.x >> 6);
    if (dst >= dst0 + ndst || dst >= NN) return;
    int lane = threadIdx.x & 63;
    float dd = dis[dst];
    const f16x2* vb = (const f16x2*)t;                  // node stride 64 (128 halves / 2)
    f16x2 td = vb[(size_t)dst * 64 + lane];
    float accx = dd * (float)td[0], accy = dd * (float)td[1];
    int beg = row_ptr[dst], end = row_ptr[dst + 1];
    for (int c = beg; c < end; c += 64) {
        int n = end - c; if (n > 64) n = 64;
        int li = (lane < n) ? csr_src[c + lane] : 0;
        float lns = (lane < n) ? dis[li] : 0.f;
        for (int j = 0; j < n; j += 4) {
            int j1 = j + 1 < n ? j + 1 : n - 1;
            int j2 = j + 2 < n ? j + 2 : n - 1;
            int j3 = j + 3 < n ? j + 3 : n - 1;
            int s0 = __shfl(li, j),  s1 = __shfl(li, j1);
            int s2 = __shfl(li, j2), s3 = __shfl(li, j3);
            float w0 = __shfl(lns, j);
            float w1 = (j + 1 < n) ? __shfl(lns, j1) : 0.f;
            float w2 = (j + 2 < n) ? __shfl(lns, j2) : 0.f;
            float w3 = (j + 3 < n) ? __shfl(lns, j3) : 0.f;
            f16x2 v0 = vb[(size_t)s0 * 64 + lane];
            f16x2 v1 = vb[(size_t)s1 * 64 + lane];
            f16x2 v2 = vb[(size_t)s2 * 64 + lane];
            f16x2 v3 = vb[(size_t)s3 * 64 + lane];
            accx += w0 * (float)v0[0] + w1 * (float)v1[0]
                  + w2 * (float)v2[0] + w3 * (float)v3[0];
            accy += w0 * (float)v0[1] + w1 * (float)v1[1]
                  + w2 * (float)v2[1] + w3 * (float)v3[1];
        }
    }
    float2 bb = *(const float2*)(b2 + lane * 2);
    float vx = dd * accx + bb.x;
    float vy = dd * accy + bb.y;
    float2 o;
    o.x = 1.0f / (1.0f + __expf(-vx));
    o.y = 1.0f / (1.0f + __expf(-vy));
    *(float2*)(out + (size_t)dst * LATD + lane * 2) = o;
}

// ---- GEMM1: h = relu(Ah @ W1T^T + b1), 128x128 tile, BK=64 (2x32 slices),
//      XCD swizzle, single-buffer (proven structure), split into 4 dispatches. ----
__global__ __launch_bounds__(256, 2) void k_gemm1(
    const _Float16* __restrict__ A,    // [M_PAD][512]
    const _Float16* __restrict__ Bt,   // [2048][512]
    const float* __restrict__ bias,    // [2000] raw b1
    _Float16* __restrict__ Ch,         // [M_PAD][2048]
    int mT0, int slab)
{
    const int b = blockIdx.x;
    const int mT = mT0 + (b & 7) * slab + ((b >> 3) >> 4);
    const int nT = (b >> 3) & 15;
    const int mBase = mT * 128;
    const int nBase = nT * 128;

    __shared__ __align__(16) _Float16 As[2 * 128 * 32];   // 16 KB: [slice][128][32]
    __shared__ __align__(16) _Float16 Bs[2 * 128 * 32];

    const int tid = threadIdx.x;
    const int lane = tid & 63;
    const int w = tid >> 6;

    const int srow = w * 32 + (lane >> 2);   // + (0|16) per chunk
    const int scol = (lane & 3) * 8;
    const _Float16* Ag0 = A + (size_t)(mBase + srow) * IND + scol;
    const _Float16* Ag1 = Ag0 + (size_t)16 * IND;
    const _Float16* Bg0 = Bt + (size_t)(nBase + srow) * IND + scol;
    const _Float16* Bg1 = Bg0 + (size_t)16 * IND;

    const int wm = (w >> 1) * 64;
    const int wn = (w & 1) * 64;
    const int lm = lane & 15;
    const int quad = lane >> 4;

    f32x4 acc[4][4];
    #pragma unroll
    for (int i = 0; i < 4; ++i)
        #pragma unroll
        for (int j = 0; j < 4; ++j)
            acc[i][j] = (f32x4){0.f, 0.f, 0.f, 0.f};

    for (int k0 = 0; k0 < IND; k0 += 64) {
        #pragma unroll
        for (int s = 0; s < 2; ++s) {
            gload_lds16(Ag0 + k0 + s * 32, As + s * 4096 + w * 1024);
            gload_lds16(Ag1 + k0 + s * 32, As + s * 4096 + w * 1024 + 512);
            gload_lds16(Bg0 + k0 + s * 32, Bs + s * 4096 + w * 1024);
            gload_lds16(Bg1 + k0 + s * 32, Bs + s * 4096 + w * 1024 + 512);
        }
        __syncthreads();

        #pragma unroll
        for (int s = 0; s < 2; ++s) {
            f16x8 af[4], bfr[4];
            #pragma unroll
            for (int mi = 0; mi < 4; ++mi)
                af[mi] = *(const f16x8*)&As[s * 4096 + (wm + mi * 16 + lm) * 32 + quad * 8];
            #pragma unroll
            for (int ni = 0; ni < 4; ++ni)
                bfr[ni] = *(const f16x8*)&Bs[s * 4096 + (wn + ni * 16 + lm) * 32 + quad * 8];
            #pragma unroll
            for (int mi = 0; mi < 4; ++mi)
                #pragma unroll
                for (int ni = 0; ni < 4; ++ni)
                    acc[mi][ni] = __builtin_amdgcn_mfma_f32_16x16x32_f16(
                        af[mi], bfr[ni], acc[mi][ni], 0, 0, 0);
        }
        __syncthreads();
    }

    #pragma unroll
    for (int mi = 0; mi < 4; ++mi) {
        #pragma unroll
        for (int ni = 0; ni < 4; ++ni) {
            int col = nBase + wn + ni * 16 + lm;
            float bval = (col < HIDD) ? bias[col] : 0.f;
            #pragma unroll
            for (int r = 0; r < 4; ++r) {
                int rowg = mBase + wm + mi * 16 + quad * 4 + r;
                float v = fmaxf(acc[mi][ni][r] + bval, 0.f);
                Ch[(size_t)rowg * N1_PAD + col] = (_Float16)v;
            }
        }
    }
}

// ---- GEMM2 split-K: Cp[ks] = h[:, ks*1024..+1024] @ W2T[:, same]^T  (f32 partials).
//      128x128 tile, BK=64, single-buffer, 16 K-steps. Grid 784 = 392 mT x 2 ks
//      -> 2-3 blocks/CU co-resident, stage/compute overlap across blocks. ----
__global__ __launch_bounds__(256, 2) void k_gemm2(
    const _Float16* __restrict__ A,    // h [M_PAD][2048]
    const _Float16* __restrict__ Bt,   // W2T [128][2048]
    float* __restrict__ Cp)            // [2][M_PAD][128] f32 partials
{
    const int b = blockIdx.x;
    const int mm = b & 391;                    // b % 392 via arithmetic below
    const int ks = b / 392;
    const int mm2 = b - ks * 392;
    const int mT = (mm2 & 7) * 49 + (mm2 >> 3);   // XCD swizzle, 392 = 8*49 exact
    const int mBase = mT * 128;
    const int kBase = ks * 1024;
    (void)mm;

    __shared__ __align__(16) _Float16 As[2 * 128 * 32];   // 16 KB
    __shared__ __align__(16) _Float16 Bs[2 * 128 * 32];   // 16 KB

    const int tid = threadIdx.x;
    const int lane = tid & 63;
    const int w = tid >> 6;

    const int srow = w * 32 + (lane >> 2);
    const int scol = (lane & 3) * 8;
    const _Float16* Ag0 = A + (size_t)(mBase + srow) * N1_PAD + kBase + scol;
    const _Float16* Ag1 = Ag0 + (size_t)16 * N1_PAD;
    const _Float16* Bg0 = Bt + (size_t)srow * N1_PAD + kBase + scol;   // 128 rows exactly
    const _Float16* Bg1 = Bg0 + (size_t)16 * N1_PAD;

    const int wm = (w >> 1) * 64;
    const int wn = (w & 1) * 64;
    const int lm = lane & 15;
    const int quad = lane >> 4;

    f32x4 acc[4][4];
    #pragma unroll
    for (int i = 0; i < 4; ++i)
        #pragma unroll
        for (int j = 0; j < 4; ++j)
            acc[i][j] = (f32x4){0.f, 0.f, 0.f, 0.f};

    for (int k0 = 0; k0 < 1024; k0 += 64) {
        #pragma unroll
        for (int s = 0; s < 2; ++s) {
            gload_lds16(Ag0 + k0 + s * 32, As + s * 4096 + w * 1024);
            gload_lds16(Ag1 + k0 + s * 32, As + s * 4096 + w * 1024 + 512);
            gload_lds16(Bg0 + k0 + s * 32, Bs + s * 4096 + w * 1024);
            gload_lds16(Bg1 + k0 + s * 32, Bs + s * 4096 + w * 1024 + 512);
        }
        __syncthreads();

        #pragma unroll
        for (int s = 0; s < 2; ++s) {
            f16x8 af[4], bfr[4];
            #pragma unroll
            for (int mi = 0; mi < 4; ++mi)
                af[mi] = *(const f16x8*)&As[s * 4096 + (wm + mi * 16 + lm) * 32 + quad * 8];
            #pragma unroll
            for (int ni = 0; ni < 4; ++ni)
                bfr[ni] = *(const f16x8*)&Bs[s * 4096 + (wn + ni * 16 + lm) * 32 + quad * 8];
            #pragma unroll
            for (int mi = 0; mi < 4; ++mi)
                #pragma unroll
                for (int ni = 0; ni < 4; ++ni)
                    acc[mi][ni] = __builtin_amdgcn_mfma_f32_16x16x32_f16(
                        af[mi], bfr[ni], acc[mi][ni], 0, 0, 0);
        }
        __syncthreads();
    }

    float* outp = Cp + (size_t)ks * M_PAD * LATD;
    #pragma unroll
    for (int mi = 0; mi < 4; ++mi) {
        #pragma unroll
        for (int ni = 0; ni < 4; ++ni) {
            int col = wn + ni * 16 + lm;
            #pragma unroll
            for (int r = 0; r < 4; ++r) {
                int rowg = mBase + wm + mi * 16 + quad * 4 + r;
                outp[(size_t)rowg * LATD + col] = acc[mi][ni][r];
            }
        }
    }
}

// ---- t = fp16(Cp[0] + Cp[1]), 8 elems/thread ----
__global__ void k_tred(const float* __restrict__ p0, const float* __restrict__ p1,
                       _Float16* __restrict__ t, int n8) {
    int i = blockIdx.x * 256 + threadIdx.x;
    if (i < n8) {
        float4 a0 = ((const float4*)p0)[i * 2];
        float4 a1 = ((const float4*)p0)[i * 2 + 1];
        float4 b0 = ((const float4*)p1)[i * 2];
        float4 b1 = ((const float4*)p1)[i * 2 + 1];
        f16x8 o;
        o[0] = (_Float16)(a0.x + b0.x); o[1] = (_Float16)(a0.y + b0.y);
        o[2] = (_Float16)(a0.z + b0.z); o[3] = (_Float16)(a0.w + b0.w);
        o[4] = (_Float16)(a1.x + b1.x); o[5] = (_Float16)(a1.y + b1.y);
        o[6] = (_Float16)(a1.z + b1.z); o[7] = (_Float16)(a1.w + b1.w);
        ((f16x8*)t)[i] = o;
    }
}

extern "C" void kernel_launch(void* const* d_in, const int* in_sizes, int n_in,
                              void* d_out, int out_size, void* d_ws, size_t ws_size,
                              hipStream_t stream) {
    const float* x  = (const float*)d_in[0];
    const int* ei   = (const int*)d_in[1];
    const float* W1 = (const float*)d_in[2];
    const float* b1 = (const float*)d_in[3];
    const float* W2 = (const float*)d_in[4];
    const float* b2 = (const float*)d_in[5];
    float* out = (float*)d_out;

    char* p = (char*)d_ws;
    auto alloc = [&](size_t bytes) {
        char* q = p; p += (bytes + 255) & ~(size_t)255; return q;
    };
    int* deg        = (int*)alloc((size_t)NN * 4);
    int* bsum       = (int*)alloc((size_t)NBLK * 4);
    int* row_ptr    = (int*)alloc((size_t)(NN + 1) * 4);
    int* cursor     = (int*)alloc((size_t)NN * 4);
    int* csr_src    = (int*)alloc((size_t)NE * 4);
    float* dis      = (float*)alloc((size_t)NN * 4);
    _Float16* W1T   = (_Float16*)alloc((size_t)N1_PAD * IND * 2);   // [2048][512]
    _Float16* W2T   = (_Float16*)alloc((size_t)LATD * N1_PAD * 2);  // [128][2048]
    _Float16* xh    = (_Float16*)alloc((size_t)NN * IND * 2);
    _Float16* Ah    = (_Float16*)alloc((size_t)M_PAD * IND * 2);    // 51.4 MB
    _Float16* h     = (_Float16*)alloc((size_t)M_PAD * N1_PAD * 2);
    _Float16* t     = (_Float16*)alloc((size_t)M_PAD * LATD * 2);

    // gemm2 f32 partials alias Ah (dead after gemm1): 2*M_PAD*128*4 == M_PAD*512*2
    float* tp = (float*)Ah;

    hipMemsetAsync(deg,    0, (size_t)NN * 4, stream);
    hipMemsetAsync(cursor, 0, (size_t)NN * 4, stream);

    k_degree<<<(NE + 255) / 256, 256, 0, stream>>>(ei + NE, deg);
    k_bsum<<<NBLK, 256, 0, stream>>>(deg, bsum);
    k_bscan<<<1, 256, 0, stream>>>(bsum);
    k_scan_final<<<NBLK, 256, 0, stream>>>(deg, bsum, row_ptr, dis);
    k_fill<<<(NE + 255) / 256, 256, 0, stream>>>(ei, row_ptr, cursor, csr_src);

    {
        // W1 [512][2000] -> W1T [2048][512], pad cols zero-filled (no memset)
        dim3 gt1(N1_PAD / 32, IND / 32);
        k_transpose_tiled<<<gt1, 256, 0, stream>>>(W1, W1T, IND, HIDD, IND, IND, N1_PAD);
        // W2 [2000][128] -> W2T [128][2048], pad rows zero-filled (no memset)
        dim3 gt2(LATD / 32, N1_PAD / 32);
        k_transpose_tiled<<<gt2, 256, 0, stream>>>(W2, W2T, HIDD, LATD, N1_PAD, N1_PAD, LATD);
        k_xcvt<<<(NN * IND / 8 + 255) / 256, 256, 0, stream>>>(x, xh, NN * IND / 8);
    }

    // gather_x split in 2 for profiler visibility
    k_gather_x<<<6250, 256, 0, stream>>>(xh, row_ptr, csr_src, dis, Ah, 0, 25000);
    k_gather_x<<<6250, 256, 0, stream>>>(xh, row_ptr, csr_src, dis, Ah, 25000, 25000);

    // gemm1 split 4 ways for profiler visibility: mT slabs 12/12/12/13 per XCD
    k_gemm1<<<8 * 12 * 16, 256, 0, stream>>>(Ah, W1T, b1, h, 0,   12);
    k_gemm1<<<8 * 12 * 16, 256, 0, stream>>>(Ah, W1T, b1, h, 96,  12);
    k_gemm1<<<8 * 12 * 16, 256, 0, stream>>>(Ah, W1T, b1, h, 192, 12);
    k_gemm1<<<8 * 13 * 16, 256, 0, stream>>>(Ah, W1T, b1, h, 288, 13);

    // gemm2: split-K x2 into f32 partials (aliasing Ah), then reduce to fp16 t
    k_gemm2<<<784, 256, 0, stream>>>(h, W2T, tp);
    k_tred<<<(M_PAD * LATD / 8 + 255) / 256, 256, 0, stream>>>(
        tp, tp + (size_t)M_PAD * LATD, t, M_PAD * LATD / 8);

    // gather_t split in 2 for profiler visibility
    k_gather_t<<<6250, 256, 0, stream>>>(t, row_ptr, csr_src, dis, b2, out, 0, 25000);
    k_gather_t<<<6250, 256, 0, stream>>>(t, row_ptr, csr_src, dis, b2, out, 25000, 25000);
}

// Round 9
// 512.187 us; speedup vs baseline: 1.0051x; 1.0051x over previous
//
#include <hip/hip_runtime.h>
#include <hip/hip_fp16.h>

#define NN 50000
#define NE 200000
#define IND 512
#define HIDD 2000
#define LATD 128

#define M_PAD 50176    // 392*128 = 784*64
#define N1_PAD 2048    // HIDD padded (pad cols forced to exact 0)
#define NBLK 196       // ceil(NN/256)

typedef _Float16 f16x8 __attribute__((ext_vector_type(8)));
typedef _Float16 f16x2 __attribute__((ext_vector_type(2)));
typedef float f32x4 __attribute__((ext_vector_type(4)));

__device__ __forceinline__ void gload_lds16(const _Float16* g, _Float16* l) {
    __builtin_amdgcn_global_load_lds(
        (const __attribute__((address_space(1))) unsigned int*)g,
        (__attribute__((address_space(3))) unsigned int*)l,
        16, 0, 0);
}

__device__ __forceinline__ void rawbar() {
    asm volatile("" ::: "memory");
    __builtin_amdgcn_s_barrier();
    asm volatile("" ::: "memory");
}

// ---- in-degree (int): deg[col[e]] += 1 ----
__global__ void k_degree(const int* __restrict__ col, int* __restrict__ deg) {
    int e = blockIdx.x * 256 + threadIdx.x;
    if (e < NE) atomicAdd(&deg[col[e]], 1);
}

// ---- hierarchical exclusive scan: (1) per-block sums ----
__global__ void k_bsum(const int* __restrict__ deg, int* __restrict__ bsum) {
    __shared__ int sm[4];
    int i = blockIdx.x * 256 + threadIdx.x;
    int v = (i < NN) ? deg[i] : 0;
    #pragma unroll
    for (int off = 32; off; off >>= 1) v += __shfl_down(v, off, 64);
    if ((threadIdx.x & 63) == 0) sm[threadIdx.x >> 6] = v;
    __syncthreads();
    if (threadIdx.x == 0) bsum[blockIdx.x] = sm[0] + sm[1] + sm[2] + sm[3];
}

// ---- (2) exclusive scan of the 196 block sums (one block) ----
__global__ void k_bscan(int* __restrict__ bsum) {
    __shared__ int sm[256];
    int tid = threadIdx.x;
    int v = (tid < NBLK) ? bsum[tid] : 0;
    sm[tid] = v;
    __syncthreads();
    #pragma unroll
    for (int off = 1; off < 256; off <<= 1) {
        int t = (tid >= off) ? sm[tid - off] : 0;
        __syncthreads();
        sm[tid] += t;
        __syncthreads();
    }
    if (tid < NBLK) bsum[tid] = sm[tid] - v;   // exclusive
}

// ---- (3) per-block exclusive scan + offset -> row_ptr; also dis = rsqrt(deg+1) ----
__global__ void k_scan_final(const int* __restrict__ deg, const int* __restrict__ bsum,
                             int* __restrict__ row_ptr, float* __restrict__ dis) {
    __shared__ int sm[256];
    int b = blockIdx.x, tid = threadIdx.x;
    int i = b * 256 + tid;
    int v = (i < NN) ? deg[i] : 0;
    if (i < NN) dis[i] = rsqrtf((float)v + 1.0f);
    sm[tid] = v;
    __syncthreads();
    #pragma unroll
    for (int off = 1; off < 256; off <<= 1) {
        int t = (tid >= off) ? sm[tid - off] : 0;
        __syncthreads();
        sm[tid] += t;
        __syncthreads();
    }
    if (i < NN) row_ptr[i] = bsum[b] + sm[tid] - v;
    if (i == NN - 1) row_ptr[NN] = bsum[b] + sm[tid];
}

// ---- fill CSR: csr_src[row_ptr[c] + cursor[c]++] = r ----
__global__ void k_fill(const int* __restrict__ ei, const int* __restrict__ row_ptr,
                       int* __restrict__ cursor, int* __restrict__ csr_src) {
    int e = blockIdx.x * 256 + threadIdx.x;
    if (e < NE) {
        int r = ei[e], c = ei[NE + e];
        int pos = atomicAdd(&cursor[c], 1);
        csr_src[row_ptr[c] + pos] = r;
    }
}

// ---- LDS-tiled transpose+convert: in f32 [R][C] -> out fp16, out[c*ldo + r].
//      Writes the FULL padded range, zero-filling pads (no separate memset). ----
__global__ void k_transpose_tiled(const float* __restrict__ in,
                                  _Float16* __restrict__ out, int R, int C, int ldo,
                                  int Rpad, int Cpad) {
    __shared__ float sm[32][33];
    int c0 = blockIdx.x * 32, r0 = blockIdx.y * 32;
    int tx = threadIdx.x & 31, ty = threadIdx.x >> 5;   // 32 x 8
    #pragma unroll
    for (int i = 0; i < 4; ++i) {
        int r = r0 + ty + i * 8, c = c0 + tx;
        sm[ty + i * 8][tx] = (r < R && c < C) ? in[(size_t)r * C + c] : 0.f;
    }
    __syncthreads();
    #pragma unroll
    for (int i = 0; i < 4; ++i) {
        int c = c0 + ty + i * 8, r = r0 + tx;
        if (c < Cpad && r < Rpad) out[(size_t)c * ldo + r] = (_Float16)sm[tx][ty + i * 8];
    }
}

// ---- x f32 -> xh fp16 (8 elems/thread) ----
__global__ void k_xcvt(const float* __restrict__ in, _Float16* __restrict__ out, int n8) {
    int i = blockIdx.x * 256 + threadIdx.x;
    if (i < n8) {
        float4 a = ((const float4*)in)[i * 2];
        float4 b = ((const float4*)in)[i * 2 + 1];
        f16x8 o;
        o[0] = (_Float16)a.x; o[1] = (_Float16)a.y; o[2] = (_Float16)a.z; o[3] = (_Float16)a.w;
        o[4] = (_Float16)b.x; o[5] = (_Float16)b.y; o[6] = (_Float16)b.z; o[7] = (_Float16)b.w;
        ((f16x8*)out)[i] = o;
    }
}

// ---- gather-aggregate x (fp16 src), 4-wide independent load slots.
//      dst range [dst0, dst0+ndst) for split-dispatch profiling. ----
__global__ void k_gather_x(const _Float16* __restrict__ xh, const int* __restrict__ row_ptr,
                           const int* __restrict__ csr_src, const float* __restrict__ dis,
                           _Float16* __restrict__ Ah, int dst0, int ndst) {
    int dst = dst0 + blockIdx.x * 4 + (threadIdx.x >> 6);
    if (dst >= dst0 + ndst || dst >= NN) return;
    int lane = threadIdx.x & 63;
    float dd = dis[dst];
    const f16x8* vb = (const f16x8*)xh;                 // node stride 64 (512 halves / 8)
    f16x8 sv = vb[(size_t)dst * 64 + lane];
    float acc[8];
    #pragma unroll
    for (int q = 0; q < 8; ++q) acc[q] = dd * (float)sv[q];
    int beg = row_ptr[dst], end = row_ptr[dst + 1];
    for (int c = beg; c < end; c += 64) {
        int n = end - c; if (n > 64) n = 64;
        int li = (lane < n) ? csr_src[c + lane] : 0;    // lane-parallel idx load
        float lns = (lane < n) ? dis[li] : 0.f;         // lane-parallel dis gather
        for (int j = 0; j < n; j += 4) {
            int j1 = j + 1 < n ? j + 1 : n - 1;
            int j2 = j + 2 < n ? j + 2 : n - 1;
            int j3 = j + 3 < n ? j + 3 : n - 1;
            int s0 = __shfl(li, j),  s1 = __shfl(li, j1);
            int s2 = __shfl(li, j2), s3 = __shfl(li, j3);
            float w0 = __shfl(lns, j);
            float w1 = (j + 1 < n) ? __shfl(lns, j1) : 0.f;
            float w2 = (j + 2 < n) ? __shfl(lns, j2) : 0.f;
            float w3 = (j + 3 < n) ? __shfl(lns, j3) : 0.f;
            f16x8 v0 = vb[(size_t)s0 * 64 + lane];
            f16x8 v1 = vb[(size_t)s1 * 64 + lane];
            f16x8 v2 = vb[(size_t)s2 * 64 + lane];
            f16x8 v3 = vb[(size_t)s3 * 64 + lane];
            #pragma unroll
            for (int q = 0; q < 8; ++q)
                acc[q] += w0 * (float)v0[q] + w1 * (float)v1[q]
                        + w2 * (float)v2[q] + w3 * (float)v3[q];
        }
    }
    f16x8 o;
    #pragma unroll
    for (int q = 0; q < 8; ++q) o[q] = (_Float16)(dd * acc[q]);
    *(f16x8*)(Ah + (size_t)dst * IND + lane * 8) = o;
}

// ---- gather-aggregate t (fp16) + bias + sigmoid -> out (f32), 4-wide slots ----
__global__ void k_gather_t(const _Float16* __restrict__ t, const int* __restrict__ row_ptr,
                           const int* __restrict__ csr_src, const float* __restrict__ dis,
                           const float* __restrict__ b2, float* __restrict__ out,
                           int dst0, int ndst) {
    int dst = dst0 + blockIdx.x * 4 + (threadIdx.x >> 6);
    if (dst >= dst0 + ndst || dst >= NN) return;
    int lane = threadIdx.x & 63;
    float dd = dis[dst];
    const f16x2* vb = (const f16x2*)t;                  // node stride 64 (128 halves / 2)
    f16x2 td = vb[(size_t)dst * 64 + lane];
    float accx = dd * (float)td[0], accy = dd * (float)td[1];
    int beg = row_ptr[dst], end = row_ptr[dst + 1];
    for (int c = beg; c < end; c += 64) {
        int n = end - c; if (n > 64) n = 64;
        int li = (lane < n) ? csr_src[c + lane] : 0;
        float lns = (lane < n) ? dis[li] : 0.f;
        for (int j = 0; j < n; j += 4) {
            int j1 = j + 1 < n ? j + 1 : n - 1;
            int j2 = j + 2 < n ? j + 2 : n - 1;
            int j3 = j + 3 < n ? j + 3 : n - 1;
            int s0 = __shfl(li, j),  s1 = __shfl(li, j1);
            int s2 = __shfl(li, j2), s3 = __shfl(li, j3);
            float w0 = __shfl(lns, j);
            float w1 = (j + 1 < n) ? __shfl(lns, j1) : 0.f;
            float w2 = (j + 2 < n) ? __shfl(lns, j2) : 0.f;
            float w3 = (j + 3 < n) ? __shfl(lns, j3) : 0.f;
            f16x2 v0 = vb[(size_t)s0 * 64 + lane];
            f16x2 v1 = vb[(size_t)s1 * 64 + lane];
            f16x2 v2 = vb[(size_t)s2 * 64 + lane];
            f16x2 v3 = vb[(size_t)s3 * 64 + lane];
            accx += w0 * (float)v0[0] + w1 * (float)v1[0]
                  + w2 * (float)v2[0] + w3 * (float)v3[0];
            accy += w0 * (float)v0[1] + w1 * (float)v1[1]
                  + w2 * (float)v2[1] + w3 * (float)v3[1];
        }
    }
    float2 bb = *(const float2*)(b2 + lane * 2);
    float vx = dd * accx + bb.x;
    float vy = dd * accy + bb.y;
    float2 o;
    o.x = 1.0f / (1.0f + __expf(-vx));
    o.y = 1.0f / (1.0f + __expf(-vy));
    *(float2*)(out + (size_t)dst * LATD + lane * 2) = o;
}

// ---- GEMM1: h = relu(Ah @ W1T^T + b1), 128x128 tile, BK=64 (2x32 slices),
//      XCD swizzle, single-buffer (proven structure), split into 4 dispatches. ----
__global__ __launch_bounds__(256, 2) void k_gemm1(
    const _Float16* __restrict__ A,    // [M_PAD][512]
    const _Float16* __restrict__ Bt,   // [2048][512]
    const float* __restrict__ bias,    // [2000] raw b1
    _Float16* __restrict__ Ch,         // [M_PAD][2048]
    int mT0, int slab)
{
    const int b = blockIdx.x;
    const int mT = mT0 + (b & 7) * slab + ((b >> 3) >> 4);
    const int nT = (b >> 3) & 15;
    const int mBase = mT * 128;
    const int nBase = nT * 128;

    __shared__ __align__(16) _Float16 As[2 * 128 * 32];   // 16 KB: [slice][128][32]
    __shared__ __align__(16) _Float16 Bs[2 * 128 * 32];

    const int tid = threadIdx.x;
    const int lane = tid & 63;
    const int w = tid >> 6;

    const int srow = w * 32 + (lane >> 2);   // + (0|16) per chunk
    const int scol = (lane & 3) * 8;
    const _Float16* Ag0 = A + (size_t)(mBase + srow) * IND + scol;
    const _Float16* Ag1 = Ag0 + (size_t)16 * IND;
    const _Float16* Bg0 = Bt + (size_t)(nBase + srow) * IND + scol;
    const _Float16* Bg1 = Bg0 + (size_t)16 * IND;

    const int wm = (w >> 1) * 64;
    const int wn = (w & 1) * 64;
    const int lm = lane & 15;
    const int quad = lane >> 4;

    f32x4 acc[4][4];
    #pragma unroll
    for (int i = 0; i < 4; ++i)
        #pragma unroll
        for (int j = 0; j < 4; ++j)
            acc[i][j] = (f32x4){0.f, 0.f, 0.f, 0.f};

    for (int k0 = 0; k0 < IND; k0 += 64) {
        #pragma unroll
        for (int s = 0; s < 2; ++s) {
            gload_lds16(Ag0 + k0 + s * 32, As + s * 4096 + w * 1024);
            gload_lds16(Ag1 + k0 + s * 32, As + s * 4096 + w * 1024 + 512);
            gload_lds16(Bg0 + k0 + s * 32, Bs + s * 4096 + w * 1024);
            gload_lds16(Bg1 + k0 + s * 32, Bs + s * 4096 + w * 1024 + 512);
        }
        __syncthreads();

        #pragma unroll
        for (int s = 0; s < 2; ++s) {
            f16x8 af[4], bfr[4];
            #pragma unroll
            for (int mi = 0; mi < 4; ++mi)
                af[mi] = *(const f16x8*)&As[s * 4096 + (wm + mi * 16 + lm) * 32 + quad * 8];
            #pragma unroll
            for (int ni = 0; ni < 4; ++ni)
                bfr[ni] = *(const f16x8*)&Bs[s * 4096 + (wn + ni * 16 + lm) * 32 + quad * 8];
            #pragma unroll
            for (int mi = 0; mi < 4; ++mi)
                #pragma unroll
                for (int ni = 0; ni < 4; ++ni)
                    acc[mi][ni] = __builtin_amdgcn_mfma_f32_16x16x32_f16(
                        af[mi], bfr[ni], acc[mi][ni], 0, 0, 0);
        }
        __syncthreads();
    }

    #pragma unroll
    for (int mi = 0; mi < 4; ++mi) {
        #pragma unroll
        for (int ni = 0; ni < 4; ++ni) {
            int col = nBase + wn + ni * 16 + lm;
            float bval = (col < HIDD) ? bias[col] : 0.f;
            #pragma unroll
            for (int r = 0; r < 4; ++r) {
                int rowg = mBase + wm + mi * 16 + quad * 4 + r;
                float v = fmaxf(acc[mi][ni][r] + bval, 0.f);
                Ch[(size_t)rowg * N1_PAD + col] = (_Float16)v;
            }
        }
    }
}

// ---- GEMM2 split-K, T4 counted-vmcnt pipeline:
//      Cp[ks] = h[:, ks*1024..+1024] @ W2T[:, same]^T  (f32 partials).
//      128x128 tile, BK=64, DOUBLE-buffered LDS (64 KB), raw barriers,
//      vmcnt(8) keeps one tile (8 loads/wave) in flight across barriers —
//      the next tile's stage latency hides under the current compute.
//      Grid 784 = 392 mT x 2 ks. ----
__global__ __launch_bounds__(256, 2) void k_gemm2(
    const _Float16* __restrict__ A,    // h [M_PAD][2048]
    const _Float16* __restrict__ Bt,   // W2T [128][2048]
    float* __restrict__ Cp)            // [2][M_PAD][128] f32 partials
{
    const int b = blockIdx.x;
    const int ks = b / 392;
    const int mm2 = b - ks * 392;
    const int mT = (mm2 & 7) * 49 + (mm2 >> 3);   // XCD swizzle, 392 = 8*49 exact
    const int mBase = mT * 128;
    const int kBase = ks * 1024;

    __shared__ __align__(16) _Float16 As[2 * 8192];   // 32 KB: [buf][slice][128][32]
    __shared__ __align__(16) _Float16 Bs[2 * 8192];   // 32 KB

    const int tid = threadIdx.x;
    const int lane = tid & 63;
    const int w = tid >> 6;

    const int srow = w * 32 + (lane >> 2);
    const int scol = (lane & 3) * 8;
    const _Float16* Ag0 = A + (size_t)(mBase + srow) * N1_PAD + kBase + scol;
    const _Float16* Ag1 = Ag0 + (size_t)16 * N1_PAD;
    const _Float16* Bg0 = Bt + (size_t)srow * N1_PAD + kBase + scol;   // 128 rows exactly
    const _Float16* Bg1 = Bg0 + (size_t)16 * N1_PAD;

    const int wm = (w >> 1) * 64;
    const int wn = (w & 1) * 64;
    const int lm = lane & 15;
    const int quad = lane >> 4;

    f32x4 acc[4][4];
    #pragma unroll
    for (int i = 0; i < 4; ++i)
        #pragma unroll
        for (int j = 0; j < 4; ++j)
            acc[i][j] = (f32x4){0.f, 0.f, 0.f, 0.f};

    auto STAGE = [&](int buf, int k0) {
        #pragma unroll
        for (int s = 0; s < 2; ++s) {
            gload_lds16(Ag0 + k0 + s * 32, As + buf * 8192 + s * 4096 + w * 1024);
            gload_lds16(Ag1 + k0 + s * 32, As + buf * 8192 + s * 4096 + w * 1024 + 512);
            gload_lds16(Bg0 + k0 + s * 32, Bs + buf * 8192 + s * 4096 + w * 1024);
            gload_lds16(Bg1 + k0 + s * 32, Bs + buf * 8192 + s * 4096 + w * 1024 + 512);
        }
    };
    auto COMPUTE = [&](int buf) {
        #pragma unroll
        for (int s = 0; s < 2; ++s) {
            f16x8 af[4], bfr[4];
            #pragma unroll
            for (int mi = 0; mi < 4; ++mi)
                af[mi] = *(const f16x8*)&As[buf * 8192 + s * 4096 + (wm + mi * 16 + lm) * 32 + quad * 8];
            #pragma unroll
            for (int ni = 0; ni < 4; ++ni)
                bfr[ni] = *(const f16x8*)&Bs[buf * 8192 + s * 4096 + (wn + ni * 16 + lm) * 32 + quad * 8];
            #pragma unroll
            for (int mi = 0; mi < 4; ++mi)
                #pragma unroll
                for (int ni = 0; ni < 4; ++ni)
                    acc[mi][ni] = __builtin_amdgcn_mfma_f32_16x16x32_f16(
                        af[mi], bfr[ni], acc[mi][ni], 0, 0, 0);
        }
    };

    // 16 K-tiles of 64. Prologue: stage tiles 0,1; wait tile 0 (oldest 8 loads).
    STAGE(0, 0);
    STAGE(1, 64);
    asm volatile("s_waitcnt vmcnt(8)" ::: "memory");
    rawbar();

    #pragma unroll 1
    for (int t = 0; t < 7; ++t) {
        // compute tile 2t (buf0); its ds_reads done -> buf0 free -> stage 2t+2
        COMPUTE(0);
        asm volatile("s_waitcnt lgkmcnt(0)" ::: "memory");
        rawbar();
        STAGE(0, (2 * t + 2) * 64);
        asm volatile("s_waitcnt vmcnt(8)" ::: "memory");   // tile 2t+1 landed
        rawbar();
        // compute tile 2t+1 (buf1); stage 2t+3
        COMPUTE(1);
        asm volatile("s_waitcnt lgkmcnt(0)" ::: "memory");
        rawbar();
        STAGE(1, (2 * t + 3) * 64);
        asm volatile("s_waitcnt vmcnt(8)" ::: "memory");   // tile 2t+2 landed
        rawbar();
    }
    COMPUTE(0);                                            // tile 14
    asm volatile("s_waitcnt vmcnt(0)" ::: "memory");       // tile 15 landed
    rawbar();
    COMPUTE(1);                                            // tile 15

    float* outp = Cp + (size_t)ks * M_PAD * LATD;
    #pragma unroll
    for (int mi = 0; mi < 4; ++mi) {
        #pragma unroll
        for (int ni = 0; ni < 4; ++ni) {
            int col = wn + ni * 16 + lm;
            #pragma unroll
            for (int r = 0; r < 4; ++r) {
                int rowg = mBase + wm + mi * 16 + quad * 4 + r;
                outp[(size_t)rowg * LATD + col] = acc[mi][ni][r];
            }
        }
    }
}

// ---- t = fp16(Cp[0] + Cp[1]), 8 elems/thread ----
__global__ void k_tred(const float* __restrict__ p0, const float* __restrict__ p1,
                       _Float16* __restrict__ t, int n8) {
    int i = blockIdx.x * 256 + threadIdx.x;
    if (i < n8) {
        float4 a0 = ((const float4*)p0)[i * 2];
        float4 a1 = ((const float4*)p0)[i * 2 + 1];
        float4 b0 = ((const float4*)p1)[i * 2];
        float4 b1 = ((const float4*)p1)[i * 2 + 1];
        f16x8 o;
        o[0] = (_Float16)(a0.x + b0.x); o[1] = (_Float16)(a0.y + b0.y);
        o[2] = (_Float16)(a0.z + b0.z); o[3] = (_Float16)(a0.w + b0.w);
        o[4] = (_Float16)(a1.x + b1.x); o[5] = (_Float16)(a1.y + b1.y);
        o[6] = (_Float16)(a1.z + b1.z); o[7] = (_Float16)(a1.w + b1.w);
        ((f16x8*)t)[i] = o;
    }
}

extern "C" void kernel_launch(void* const* d_in, const int* in_sizes, int n_in,
                              void* d_out, int out_size, void* d_ws, size_t ws_size,
                              hipStream_t stream) {
    const float* x  = (const float*)d_in[0];
    const int* ei   = (const int*)d_in[1];
    const float* W1 = (const float*)d_in[2];
    const float* b1 = (const float*)d_in[3];
    const float* W2 = (const float*)d_in[4];
    const float* b2 = (const float*)d_in[5];
    float* out = (float*)d_out;

    char* p = (char*)d_ws;
    auto alloc = [&](size_t bytes) {
        char* q = p; p += (bytes + 255) & ~(size_t)255; return q;
    };
    int* deg        = (int*)alloc((size_t)NN * 4);
    int* bsum       = (int*)alloc((size_t)NBLK * 4);
    int* row_ptr    = (int*)alloc((size_t)(NN + 1) * 4);
    int* cursor     = (int*)alloc((size_t)NN * 4);
    int* csr_src    = (int*)alloc((size_t)NE * 4);
    float* dis      = (float*)alloc((size_t)NN * 4);
    _Float16* W1T   = (_Float16*)alloc((size_t)N1_PAD * IND * 2);   // [2048][512]
    _Float16* W2T   = (_Float16*)alloc((size_t)LATD * N1_PAD * 2);  // [128][2048]
    _Float16* xh    = (_Float16*)alloc((size_t)NN * IND * 2);
    _Float16* Ah    = (_Float16*)alloc((size_t)M_PAD * IND * 2);    // 51.4 MB
    _Float16* h     = (_Float16*)alloc((size_t)M_PAD * N1_PAD * 2);
    _Float16* t     = (_Float16*)alloc((size_t)M_PAD * LATD * 2);

    // gemm2 f32 partials alias Ah (dead after gemm1): 2*M_PAD*128*4 == M_PAD*512*2
    float* tp = (float*)Ah;

    hipMemsetAsync(deg,    0, (size_t)NN * 4, stream);
    hipMemsetAsync(cursor, 0, (size_t)NN * 4, stream);

    k_degree<<<(NE + 255) / 256, 256, 0, stream>>>(ei + NE, deg);
    k_bsum<<<NBLK, 256, 0, stream>>>(deg, bsum);
    k_bscan<<<1, 256, 0, stream>>>(bsum);
    k_scan_final<<<NBLK, 256, 0, stream>>>(deg, bsum, row_ptr, dis);
    k_fill<<<(NE + 255) / 256, 256, 0, stream>>>(ei, row_ptr, cursor, csr_src);

    {
        // W1 [512][2000] -> W1T [2048][512], pad cols zero-filled (no memset)
        dim3 gt1(N1_PAD / 32, IND / 32);
        k_transpose_tiled<<<gt1, 256, 0, stream>>>(W1, W1T, IND, HIDD, IND, IND, N1_PAD);
        // W2 [2000][128] -> W2T [128][2048], pad rows zero-filled (no memset)
        dim3 gt2(LATD / 32, N1_PAD / 32);
        k_transpose_tiled<<<gt2, 256, 0, stream>>>(W2, W2T, HIDD, LATD, N1_PAD, N1_PAD, LATD);
        k_xcvt<<<(NN * IND / 8 + 255) / 256, 256, 0, stream>>>(x, xh, NN * IND / 8);
    }

    // gather_x split in 2 for profiler visibility
    k_gather_x<<<6250, 256, 0, stream>>>(xh, row_ptr, csr_src, dis, Ah, 0, 25000);
    k_gather_x<<<6250, 256, 0, stream>>>(xh, row_ptr, csr_src, dis, Ah, 25000, 25000);

    // gemm1 split 4 ways for profiler visibility: mT slabs 12/12/12/13 per XCD
    k_gemm1<<<8 * 12 * 16, 256, 0, stream>>>(Ah, W1T, b1, h, 0,   12);
    k_gemm1<<<8 * 12 * 16, 256, 0, stream>>>(Ah, W1T, b1, h, 96,  12);
    k_gemm1<<<8 * 12 * 16, 256, 0, stream>>>(Ah, W1T, b1, h, 192, 12);
    k_gemm1<<<8 * 13 * 16, 256, 0, stream>>>(Ah, W1T, b1, h, 288, 13);

    // gemm2: split-K x2 into f32 partials (aliasing Ah), then reduce to fp16 t
    k_gemm2<<<784, 256, 0, stream>>>(h, W2T, tp);
    k_tred<<<(M_PAD * LATD / 8 + 255) / 256, 256, 0, stream>>>(
        tp, tp + (size_t)M_PAD * LATD, t, M_PAD * LATD / 8);

    // gather_t split in 2 for profiler visibility
    k_gather_t<<<6250, 256, 0, stream>>>(t, row_ptr, csr_src, dis, b2, out, 0, 25000);
    k_gather_t<<<6250, 256, 0, stream>>>(t, row_ptr, csr_src, dis, b2, out, 25000, 25000);
}

// Round 10
// 504.939 us; speedup vs baseline: 1.0195x; 1.0144x over previous
//
#include <hip/hip_runtime.h>
#include <hip/hip_fp16.h>

#define NN 50000
#define NE 200000
#define IND 512
#define HIDD 2000
#define LATD 128

#define M_PAD 50176    // 392*128 = 784*64
#define N1_PAD 2048    // HIDD padded (pad cols forced to exact 0)
#define NBLK 196       // ceil(NN/256)

typedef _Float16 f16x8 __attribute__((ext_vector_type(8)));
typedef _Float16 f16x2 __attribute__((ext_vector_type(2)));
typedef float f32x4 __attribute__((ext_vector_type(4)));

__device__ __forceinline__ void gload_lds16(const _Float16* g, _Float16* l) {
    __builtin_amdgcn_global_load_lds(
        (const __attribute__((address_space(1))) unsigned int*)g,
        (__attribute__((address_space(3))) unsigned int*)l,
        16, 0, 0);
}

// ---- in-degree (int): deg[col[e]] += 1 ----
__global__ void k_degree(const int* __restrict__ col, int* __restrict__ deg) {
    int e = blockIdx.x * 256 + threadIdx.x;
    if (e < NE) atomicAdd(&deg[col[e]], 1);
}

// ---- hierarchical exclusive scan: (1) per-block sums ----
__global__ void k_bsum(const int* __restrict__ deg, int* __restrict__ bsum) {
    __shared__ int sm[4];
    int i = blockIdx.x * 256 + threadIdx.x;
    int v = (i < NN) ? deg[i] : 0;
    #pragma unroll
    for (int off = 32; off; off >>= 1) v += __shfl_down(v, off, 64);
    if ((threadIdx.x & 63) == 0) sm[threadIdx.x >> 6] = v;
    __syncthreads();
    if (threadIdx.x == 0) bsum[blockIdx.x] = sm[0] + sm[1] + sm[2] + sm[3];
}

// ---- (2) exclusive scan of the 196 block sums (one block) ----
__global__ void k_bscan(int* __restrict__ bsum) {
    __shared__ int sm[256];
    int tid = threadIdx.x;
    int v = (tid < NBLK) ? bsum[tid] : 0;
    sm[tid] = v;
    __syncthreads();
    #pragma unroll
    for (int off = 1; off < 256; off <<= 1) {
        int t = (tid >= off) ? sm[tid - off] : 0;
        __syncthreads();
        sm[tid] += t;
        __syncthreads();
    }
    if (tid < NBLK) bsum[tid] = sm[tid] - v;   // exclusive
}

// ---- (3) per-block exclusive scan + offset -> row_ptr; also dis = rsqrt(deg+1) ----
__global__ void k_scan_final(const int* __restrict__ deg, const int* __restrict__ bsum,
                             int* __restrict__ row_ptr, float* __restrict__ dis) {
    __shared__ int sm[256];
    int b = blockIdx.x, tid = threadIdx.x;
    int i = b * 256 + tid;
    int v = (i < NN) ? deg[i] : 0;
    if (i < NN) dis[i] = rsqrtf((float)v + 1.0f);
    sm[tid] = v;
    __syncthreads();
    #pragma unroll
    for (int off = 1; off < 256; off <<= 1) {
        int t = (tid >= off) ? sm[tid - off] : 0;
        __syncthreads();
        sm[tid] += t;
        __syncthreads();
    }
    if (i < NN) row_ptr[i] = bsum[b] + sm[tid] - v;
    if (i == NN - 1) row_ptr[NN] = bsum[b] + sm[tid];
}

// ---- fill CSR: csr_src[row_ptr[c] + cursor[c]++] = r ----
__global__ void k_fill(const int* __restrict__ ei, const int* __restrict__ row_ptr,
                       int* __restrict__ cursor, int* __restrict__ csr_src) {
    int e = blockIdx.x * 256 + threadIdx.x;
    if (e < NE) {
        int r = ei[e], c = ei[NE + e];
        int pos = atomicAdd(&cursor[c], 1);
        csr_src[row_ptr[c] + pos] = r;
    }
}

// ---- LDS-tiled transpose+convert: in f32 [R][C] -> out fp16, out[c*ldo + r].
//      Writes the FULL padded range, zero-filling pads (no separate memset). ----
__global__ void k_transpose_tiled(const float* __restrict__ in,
                                  _Float16* __restrict__ out, int R, int C, int ldo,
                                  int Rpad, int Cpad) {
    __shared__ float sm[32][33];
    int c0 = blockIdx.x * 32, r0 = blockIdx.y * 32;
    int tx = threadIdx.x & 31, ty = threadIdx.x >> 5;   // 32 x 8
    #pragma unroll
    for (int i = 0; i < 4; ++i) {
        int r = r0 + ty + i * 8, c = c0 + tx;
        sm[ty + i * 8][tx] = (r < R && c < C) ? in[(size_t)r * C + c] : 0.f;
    }
    __syncthreads();
    #pragma unroll
    for (int i = 0; i < 4; ++i) {
        int c = c0 + ty + i * 8, r = r0 + tx;
        if (c < Cpad && r < Rpad) out[(size_t)c * ldo + r] = (_Float16)sm[tx][ty + i * 8];
    }
}

// ---- x f32 -> xh fp16 (8 elems/thread) ----
__global__ void k_xcvt(const float* __restrict__ in, _Float16* __restrict__ out, int n8) {
    int i = blockIdx.x * 256 + threadIdx.x;
    if (i < n8) {
        float4 a = ((const float4*)in)[i * 2];
        float4 b = ((const float4*)in)[i * 2 + 1];
        f16x8 o;
        o[0] = (_Float16)a.x; o[1] = (_Float16)a.y; o[2] = (_Float16)a.z; o[3] = (_Float16)a.w;
        o[4] = (_Float16)b.x; o[5] = (_Float16)b.y; o[6] = (_Float16)b.z; o[7] = (_Float16)b.w;
        ((f16x8*)out)[i] = o;
    }
}

// ---- gather-aggregate x (fp16 src), DUAL-ROW per wave, 4-wide slots per row:
//      each wave owns rows (ra, ra+1): contiguous CSR ranges (3 scalar row_ptr
//      loads), both rows' load groups issued back-to-back -> 8 independent
//      1KB gathers in flight. ----
__global__ void k_gather_x(const _Float16* __restrict__ xh, const int* __restrict__ row_ptr,
                           const int* __restrict__ csr_src, const float* __restrict__ dis,
                           _Float16* __restrict__ Ah) {
    int ra = blockIdx.x * 8 + (threadIdx.x >> 6) * 2;
    if (ra >= NN) return;
    int rb = ra + 1;                                    // NN even: rb < NN always
    int lane = threadIdx.x & 63;
    const f16x8* vb = (const f16x8*)xh;                 // node stride 64 (512 halves / 8)
    float dda = dis[ra], ddb = dis[rb];
    f16x8 sva = vb[(size_t)ra * 64 + lane];
    f16x8 svb = vb[(size_t)rb * 64 + lane];
    float acca[8], accb[8];
    #pragma unroll
    for (int q = 0; q < 8; ++q) { acca[q] = dda * (float)sva[q]; accb[q] = ddb * (float)svb[q]; }
    int bega = row_ptr[ra];
    int mid  = row_ptr[rb];
    int endb = row_ptr[rb + 1];
    for (int ca = bega, cb = mid; ca < mid || cb < endb; ca += 64, cb += 64) {
        int na = mid - ca;  na = na < 0 ? 0 : (na > 64 ? 64 : na);
        int nb = endb - cb; nb = nb < 0 ? 0 : (nb > 64 ? 64 : nb);
        int lia = (lane < na) ? csr_src[ca + lane] : 0;
        int lib = (lane < nb) ? csr_src[cb + lane] : 0;
        float lnsa = (lane < na) ? dis[lia] : 0.f;
        float lnsb = (lane < nb) ? dis[lib] : 0.f;
        int G = ((na > nb ? na : nb) + 3) >> 2;
        for (int g = 0; g < G; ++g) {
            int j = g * 4;
            f16x8 va0, va1, va2, va3, vb0, vb1, vb2, vb3;
            float wa0 = 0, wa1 = 0, wa2 = 0, wa3 = 0;
            float wb0 = 0, wb1 = 0, wb2 = 0, wb3 = 0;
            bool doa = j < na, dob = j < nb;
            if (doa) {
                int j1 = j + 1 < na ? j + 1 : na - 1;
                int j2 = j + 2 < na ? j + 2 : na - 1;
                int j3 = j + 3 < na ? j + 3 : na - 1;
                int s0 = __shfl(lia, j),  s1 = __shfl(lia, j1);
                int s2 = __shfl(lia, j2), s3 = __shfl(lia, j3);
                wa0 = __shfl(lnsa, j);
                wa1 = (j + 1 < na) ? __shfl(lnsa, j1) : 0.f;
                wa2 = (j + 2 < na) ? __shfl(lnsa, j2) : 0.f;
                wa3 = (j + 3 < na) ? __shfl(lnsa, j3) : 0.f;
                va0 = vb[(size_t)s0 * 64 + lane];
                va1 = vb[(size_t)s1 * 64 + lane];
                va2 = vb[(size_t)s2 * 64 + lane];
                va3 = vb[(size_t)s3 * 64 + lane];
            }
            if (dob) {
                int j1 = j + 1 < nb ? j + 1 : nb - 1;
                int j2 = j + 2 < nb ? j + 2 : nb - 1;
                int j3 = j + 3 < nb ? j + 3 : nb - 1;
                int s0 = __shfl(lib, j),  s1 = __shfl(lib, j1);
                int s2 = __shfl(lib, j2), s3 = __shfl(lib, j3);
                wb0 = __shfl(lnsb, j);
                wb1 = (j + 1 < nb) ? __shfl(lnsb, j1) : 0.f;
                wb2 = (j + 2 < nb) ? __shfl(lnsb, j2) : 0.f;
                wb3 = (j + 3 < nb) ? __shfl(lnsb, j3) : 0.f;
                vb0 = vb[(size_t)s0 * 64 + lane];
                vb1 = vb[(size_t)s1 * 64 + lane];
                vb2 = vb[(size_t)s2 * 64 + lane];
                vb3 = vb[(size_t)s3 * 64 + lane];
            }
            if (doa) {
                #pragma unroll
                for (int q = 0; q < 8; ++q)
                    acca[q] += wa0 * (float)va0[q] + wa1 * (float)va1[q]
                             + wa2 * (float)va2[q] + wa3 * (float)va3[q];
            }
            if (dob) {
                #pragma unroll
                for (int q = 0; q < 8; ++q)
                    accb[q] += wb0 * (float)vb0[q] + wb1 * (float)vb1[q]
                             + wb2 * (float)vb2[q] + wb3 * (float)vb3[q];
            }
        }
    }
    f16x8 oa, ob;
    #pragma unroll
    for (int q = 0; q < 8; ++q) {
        oa[q] = (_Float16)(dda * acca[q]);
        ob[q] = (_Float16)(ddb * accb[q]);
    }
    *(f16x8*)(Ah + (size_t)ra * IND + lane * 8) = oa;
    *(f16x8*)(Ah + (size_t)rb * IND + lane * 8) = ob;
}

// ---- gather-aggregate t (fp16) + bias + sigmoid -> out (f32), dual-row ----
__global__ void k_gather_t(const _Float16* __restrict__ t, const int* __restrict__ row_ptr,
                           const int* __restrict__ csr_src, const float* __restrict__ dis,
                           const float* __restrict__ b2, float* __restrict__ out) {
    int ra = blockIdx.x * 8 + (threadIdx.x >> 6) * 2;
    if (ra >= NN) return;
    int rb = ra + 1;
    int lane = threadIdx.x & 63;
    const f16x2* vb = (const f16x2*)t;                  // node stride 64 (128 halves / 2)
    float dda = dis[ra], ddb = dis[rb];
    f16x2 tda = vb[(size_t)ra * 64 + lane];
    f16x2 tdb = vb[(size_t)rb * 64 + lane];
    float ax = dda * (float)tda[0], ay = dda * (float)tda[1];
    float bx = ddb * (float)tdb[0], by = ddb * (float)tdb[1];
    int bega = row_ptr[ra];
    int mid  = row_ptr[rb];
    int endb = row_ptr[rb + 1];
    for (int ca = bega, cb = mid; ca < mid || cb < endb; ca += 64, cb += 64) {
        int na = mid - ca;  na = na < 0 ? 0 : (na > 64 ? 64 : na);
        int nb = endb - cb; nb = nb < 0 ? 0 : (nb > 64 ? 64 : nb);
        int lia = (lane < na) ? csr_src[ca + lane] : 0;
        int lib = (lane < nb) ? csr_src[cb + lane] : 0;
        float lnsa = (lane < na) ? dis[lia] : 0.f;
        float lnsb = (lane < nb) ? dis[lib] : 0.f;
        int G = ((na > nb ? na : nb) + 3) >> 2;
        for (int g = 0; g < G; ++g) {
            int j = g * 4;
            f16x2 va0, va1, va2, va3, vv0, vv1, vv2, vv3;
            float wa0 = 0, wa1 = 0, wa2 = 0, wa3 = 0;
            float wb0 = 0, wb1 = 0, wb2 = 0, wb3 = 0;
            bool doa = j < na, dob = j < nb;
            if (doa) {
                int j1 = j + 1 < na ? j + 1 : na - 1;
                int j2 = j + 2 < na ? j + 2 : na - 1;
                int j3 = j + 3 < na ? j + 3 : na - 1;
                int s0 = __shfl(lia, j),  s1 = __shfl(lia, j1);
                int s2 = __shfl(lia, j2), s3 = __shfl(lia, j3);
                wa0 = __shfl(lnsa, j);
                wa1 = (j + 1 < na) ? __shfl(lnsa, j1) : 0.f;
                wa2 = (j + 2 < na) ? __shfl(lnsa, j2) : 0.f;
                wa3 = (j + 3 < na) ? __shfl(lnsa, j3) : 0.f;
                va0 = vb[(size_t)s0 * 64 + lane];
                va1 = vb[(size_t)s1 * 64 + lane];
                va2 = vb[(size_t)s2 * 64 + lane];
                va3 = vb[(size_t)s3 * 64 + lane];
            }
            if (dob) {
                int j1 = j + 1 < nb ? j + 1 : nb - 1;
                int j2 = j + 2 < nb ? j + 2 : nb - 1;
                int j3 = j + 3 < nb ? j + 3 : nb - 1;
                int s0 = __shfl(lib, j),  s1 = __shfl(lib, j1);
                int s2 = __shfl(lib, j2), s3 = __shfl(lib, j3);
                wb0 = __shfl(lnsb, j);
                wb1 = (j + 1 < nb) ? __shfl(lnsb, j1) : 0.f;
                wb2 = (j + 2 < nb) ? __shfl(lnsb, j2) : 0.f;
                wb3 = (j + 3 < nb) ? __shfl(lnsb, j3) : 0.f;
                vv0 = vb[(size_t)s0 * 64 + lane];
                vv1 = vb[(size_t)s1 * 64 + lane];
                vv2 = vb[(size_t)s2 * 64 + lane];
                vv3 = vb[(size_t)s3 * 64 + lane];
            }
            if (doa) {
                ax += wa0 * (float)va0[0] + wa1 * (float)va1[0]
                    + wa2 * (float)va2[0] + wa3 * (float)va3[0];
                ay += wa0 * (float)va0[1] + wa1 * (float)va1[1]
                    + wa2 * (float)va2[1] + wa3 * (float)va3[1];
            }
            if (dob) {
                bx += wb0 * (float)vv0[0] + wb1 * (float)vv1[0]
                    + wb2 * (float)vv2[0] + wb3 * (float)vv3[0];
                by += wb0 * (float)vv0[1] + wb1 * (float)vv1[1]
                    + wb2 * (float)vv2[1] + wb3 * (float)vv3[1];
            }
        }
    }
    float2 bb = *(const float2*)(b2 + lane * 2);
    float vxa = dda * ax + bb.x, vya = dda * ay + bb.y;
    float vxb = ddb * bx + bb.x, vyb = ddb * by + bb.y;
    float2 oa, ob;
    oa.x = 1.0f / (1.0f + __expf(-vxa));
    oa.y = 1.0f / (1.0f + __expf(-vya));
    ob.x = 1.0f / (1.0f + __expf(-vxb));
    ob.y = 1.0f / (1.0f + __expf(-vyb));
    *(float2*)(out + (size_t)ra * LATD + lane * 2) = oa;
    *(float2*)(out + (size_t)rb * LATD + lane * 2) = ob;
}

// ---- GEMM1: h = relu(Ah @ W1T^T + b1), 128x128 tile, BK=64 (2x32 slices),
//      XCD swizzle, single-buffer (proven structure), split into 4 dispatches. ----
__global__ __launch_bounds__(256, 2) void k_gemm1(
    const _Float16* __restrict__ A,    // [M_PAD][512]
    const _Float16* __restrict__ Bt,   // [2048][512]
    const float* __restrict__ bias,    // [2000] raw b1
    _Float16* __restrict__ Ch,         // [M_PAD][2048]
    int mT0, int slab)
{
    const int b = blockIdx.x;
    const int mT = mT0 + (b & 7) * slab + ((b >> 3) >> 4);
    const int nT = (b >> 3) & 15;
    const int mBase = mT * 128;
    const int nBase = nT * 128;

    __shared__ __align__(16) _Float16 As[2 * 128 * 32];   // 16 KB: [slice][128][32]
    __shared__ __align__(16) _Float16 Bs[2 * 128 * 32];

    const int tid = threadIdx.x;
    const int lane = tid & 63;
    const int w = tid >> 6;

    const int srow = w * 32 + (lane >> 2);   // + (0|16) per chunk
    const int scol = (lane & 3) * 8;
    const _Float16* Ag0 = A + (size_t)(mBase + srow) * IND + scol;
    const _Float16* Ag1 = Ag0 + (size_t)16 * IND;
    const _Float16* Bg0 = Bt + (size_t)(nBase + srow) * IND + scol;
    const _Float16* Bg1 = Bg0 + (size_t)16 * IND;

    const int wm = (w >> 1) * 64;
    const int wn = (w & 1) * 64;
    const int lm = lane & 15;
    const int quad = lane >> 4;

    f32x4 acc[4][4];
    #pragma unroll
    for (int i = 0; i < 4; ++i)
        #pragma unroll
        for (int j = 0; j < 4; ++j)
            acc[i][j] = (f32x4){0.f, 0.f, 0.f, 0.f};

    for (int k0 = 0; k0 < IND; k0 += 64) {
        #pragma unroll
        for (int s = 0; s < 2; ++s) {
            gload_lds16(Ag0 + k0 + s * 32, As + s * 4096 + w * 1024);
            gload_lds16(Ag1 + k0 + s * 32, As + s * 4096 + w * 1024 + 512);
            gload_lds16(Bg0 + k0 + s * 32, Bs + s * 4096 + w * 1024);
            gload_lds16(Bg1 + k0 + s * 32, Bs + s * 4096 + w * 1024 + 512);
        }
        __syncthreads();

        #pragma unroll
        for (int s = 0; s < 2; ++s) {
            f16x8 af[4], bfr[4];
            #pragma unroll
            for (int mi = 0; mi < 4; ++mi)
                af[mi] = *(const f16x8*)&As[s * 4096 + (wm + mi * 16 + lm) * 32 + quad * 8];
            #pragma unroll
            for (int ni = 0; ni < 4; ++ni)
                bfr[ni] = *(const f16x8*)&Bs[s * 4096 + (wn + ni * 16 + lm) * 32 + quad * 8];
            #pragma unroll
            for (int mi = 0; mi < 4; ++mi)
                #pragma unroll
                for (int ni = 0; ni < 4; ++ni)
                    acc[mi][ni] = __builtin_amdgcn_mfma_f32_16x16x32_f16(
                        af[mi], bfr[ni], acc[mi][ni], 0, 0, 0);
        }
        __syncthreads();
    }

    #pragma unroll
    for (int mi = 0; mi < 4; ++mi) {
        #pragma unroll
        for (int ni = 0; ni < 4; ++ni) {
            int col = nBase + wn + ni * 16 + lm;
            float bval = (col < HIDD) ? bias[col] : 0.f;
            #pragma unroll
            for (int r = 0; r < 4; ++r) {
                int rowg = mBase + wm + mi * 16 + quad * 4 + r;
                float v = fmaxf(acc[mi][ni][r] + bval, 0.f);
                Ch[(size_t)rowg * N1_PAD + col] = (_Float16)v;
            }
        }
    }
}

// ---- GEMM2: t = h @ W2T^T  (fp16 out). Round-7 proven version:
//      128x128 tile, BK=64, single-buffer, 392 blocks, XCD swizzle. ----
__global__ __launch_bounds__(256, 2) void k_gemm2(
    const _Float16* __restrict__ A,    // h [M_PAD][2048]
    const _Float16* __restrict__ Bt,   // W2T [128][2048]
    _Float16* __restrict__ Cf)         // t fp16 [M_PAD][128]
{
    const int b = blockIdx.x;
    const int mT = (b & 7) * 49 + (b >> 3);   // XCD swizzle, 392 = 8*49 exact
    const int mBase = mT * 128;

    __shared__ __align__(16) _Float16 As[2 * 128 * 32];   // 16 KB
    __shared__ __align__(16) _Float16 Bs[2 * 128 * 32];   // 16 KB

    const int tid = threadIdx.x;
    const int lane = tid & 63;
    const int w = tid >> 6;

    const int srow = w * 32 + (lane >> 2);
    const int scol = (lane & 3) * 8;
    const _Float16* Ag0 = A + (size_t)(mBase + srow) * N1_PAD + scol;
    const _Float16* Ag1 = Ag0 + (size_t)16 * N1_PAD;
    const _Float16* Bg0 = Bt + (size_t)srow * N1_PAD + scol;   // 128 rows exactly
    const _Float16* Bg1 = Bg0 + (size_t)16 * N1_PAD;

    const int wm = (w >> 1) * 64;
    const int wn = (w & 1) * 64;
    const int lm = lane & 15;
    const int quad = lane >> 4;

    f32x4 acc[4][4];
    #pragma unroll
    for (int i = 0; i < 4; ++i)
        #pragma unroll
        for (int j = 0; j < 4; ++j)
            acc[i][j] = (f32x4){0.f, 0.f, 0.f, 0.f};

    for (int k0 = 0; k0 < N1_PAD; k0 += 64) {
        #pragma unroll
        for (int s = 0; s < 2; ++s) {
            gload_lds16(Ag0 + k0 + s * 32, As + s * 4096 + w * 1024);
            gload_lds16(Ag1 + k0 + s * 32, As + s * 4096 + w * 1024 + 512);
            gload_lds16(Bg0 + k0 + s * 32, Bs + s * 4096 + w * 1024);
            gload_lds16(Bg1 + k0 + s * 32, Bs + s * 4096 + w * 1024 + 512);
        }
        __syncthreads();

        #pragma unroll
        for (int s = 0; s < 2; ++s) {
            f16x8 af[4], bfr[4];
            #pragma unroll
            for (int mi = 0; mi < 4; ++mi)
                af[mi] = *(const f16x8*)&As[s * 4096 + (wm + mi * 16 + lm) * 32 + quad * 8];
            #pragma unroll
            for (int ni = 0; ni < 4; ++ni)
                bfr[ni] = *(const f16x8*)&Bs[s * 4096 + (wn + ni * 16 + lm) * 32 + quad * 8];
            #pragma unroll
            for (int mi = 0; mi < 4; ++mi)
                #pragma unroll
                for (int ni = 0; ni < 4; ++ni)
                    acc[mi][ni] = __builtin_amdgcn_mfma_f32_16x16x32_f16(
                        af[mi], bfr[ni], acc[mi][ni], 0, 0, 0);
        }
        __syncthreads();
    }

    #pragma unroll
    for (int mi = 0; mi < 4; ++mi) {
        #pragma unroll
        for (int ni = 0; ni < 4; ++ni) {
            int col = wn + ni * 16 + lm;
            #pragma unroll
            for (int r = 0; r < 4; ++r) {
                int rowg = mBase + wm + mi * 16 + quad * 4 + r;
                Cf[(size_t)rowg * LATD + col] = (_Float16)acc[mi][ni][r];
            }
        }
    }
}

extern "C" void kernel_launch(void* const* d_in, const int* in_sizes, int n_in,
                              void* d_out, int out_size, void* d_ws, size_t ws_size,
                              hipStream_t stream) {
    const float* x  = (const float*)d_in[0];
    const int* ei   = (const int*)d_in[1];
    const float* W1 = (const float*)d_in[2];
    const float* b1 = (const float*)d_in[3];
    const float* W2 = (const float*)d_in[4];
    const float* b2 = (const float*)d_in[5];
    float* out = (float*)d_out;

    char* p = (char*)d_ws;
    auto alloc = [&](size_t bytes) {
        char* q = p; p += (bytes + 255) & ~(size_t)255; return q;
    };
    int* deg        = (int*)alloc((size_t)NN * 4);
    int* bsum       = (int*)alloc((size_t)NBLK * 4);
    int* row_ptr    = (int*)alloc((size_t)(NN + 1) * 4);
    int* cursor     = (int*)alloc((size_t)NN * 4);
    int* csr_src    = (int*)alloc((size_t)NE * 4);
    float* dis      = (float*)alloc((size_t)NN * 4);
    _Float16* W1T   = (_Float16*)alloc((size_t)N1_PAD * IND * 2);   // [2048][512]
    _Float16* W2T   = (_Float16*)alloc((size_t)LATD * N1_PAD * 2);  // [128][2048]
    _Float16* xh    = (_Float16*)alloc((size_t)NN * IND * 2);
    _Float16* Ah    = (_Float16*)alloc((size_t)M_PAD * IND * 2);
    _Float16* h     = (_Float16*)alloc((size_t)M_PAD * N1_PAD * 2);
    _Float16* t     = (_Float16*)alloc((size_t)M_PAD * LATD * 2);

    hipMemsetAsync(deg,    0, (size_t)NN * 4, stream);
    hipMemsetAsync(cursor, 0, (size_t)NN * 4, stream);

    k_degree<<<(NE + 255) / 256, 256, 0, stream>>>(ei + NE, deg);
    k_bsum<<<NBLK, 256, 0, stream>>>(deg, bsum);
    k_bscan<<<1, 256, 0, stream>>>(bsum);
    k_scan_final<<<NBLK, 256, 0, stream>>>(deg, bsum, row_ptr, dis);
    k_fill<<<(NE + 255) / 256, 256, 0, stream>>>(ei, row_ptr, cursor, csr_src);

    {
        // W1 [512][2000] -> W1T [2048][512], pad cols zero-filled (no memset)
        dim3 gt1(N1_PAD / 32, IND / 32);
        k_transpose_tiled<<<gt1, 256, 0, stream>>>(W1, W1T, IND, HIDD, IND, IND, N1_PAD);
        // W2 [2000][128] -> W2T [128][2048], pad rows zero-filled (no memset)
        dim3 gt2(LATD / 32, N1_PAD / 32);
        k_transpose_tiled<<<gt2, 256, 0, stream>>>(W2, W2T, HIDD, LATD, N1_PAD, N1_PAD, LATD);
        k_xcvt<<<(NN * IND / 8 + 255) / 256, 256, 0, stream>>>(x, xh, NN * IND / 8);
    }

    // dual-row gathers: 8 rows per block (2 per wave), 6250 blocks = 50000 rows
    k_gather_x<<<(NN + 7) / 8, 256, 0, stream>>>(xh, row_ptr, csr_src, dis, Ah);

    // gemm1 split 4 ways for profiler visibility: mT slabs 12/12/12/13 per XCD
    k_gemm1<<<8 * 12 * 16, 256, 0, stream>>>(Ah, W1T, b1, h, 0,   12);
    k_gemm1<<<8 * 12 * 16, 256, 0, stream>>>(Ah, W1T, b1, h, 96,  12);
    k_gemm1<<<8 * 12 * 16, 256, 0, stream>>>(Ah, W1T, b1, h, 192, 12);
    k_gemm1<<<8 * 13 * 16, 256, 0, stream>>>(Ah, W1T, b1, h, 288, 13);

    k_gemm2<<<392, 256, 0, stream>>>(h, W2T, t);

    k_gather_t<<<(NN + 7) / 8, 256, 0, stream>>>(t, row_ptr, csr_src, dis, b2, out);
}